// Round 6
// baseline (2206.086 us; speedup 1.0000x reference)
//
#include <hip/hip_runtime.h>

// Fixed problem dims: NX=128, NW=64, NY=32, NLAYER=2, NWUP=256, NBATCH=1024, NHRZN=256
#define NBATCH 1024
#define TSTEPS 512
#define NWUPC  256

// Output layout in d_out (fp32, flat, concatenated in return order):
//   X    (513,1024,128) : 67239936
//   W    (256,1024, 64) : 16777216
//   Yhat (513,1024, 32) : 16809984
#define XLEN 67239936ULL
#define WLEN 16777216ULL

typedef __attribute__((ext_vector_type(8))) short bf16x8;  // 8 bf16 in 4 VGPRs
typedef __attribute__((ext_vector_type(4))) float f32x4;   // MFMA 16x16 C/D

__device__ __forceinline__ unsigned short to_bf16u(float f) {
  union { float f; unsigned u; } v; v.f = f;
  unsigned r = (v.u + 0x7FFFu + ((v.u >> 16) & 1u)) >> 16;  // RNE
  return (unsigned short)r;
}
__device__ __forceinline__ float bf16_to_f(short h) {
  union { unsigned u; float f; } v;
  v.u = ((unsigned)(unsigned short)h) << 16;
  return v.f;
}
// no clamps: |u| <~ 20 given weight scale 0.05 and bounded h; exp/tanh safe to x~44
__device__ __forceinline__ float sigm(float x) {
  return __builtin_amdgcn_rcpf(1.f + __expf(-x));
}
__device__ __forceinline__ float ftanh(float x) {
  float e = __expf(2.f * x);
  return (e - 1.f) * __builtin_amdgcn_rcpf(e + 1.f);
}

// lgkmcnt-only barrier: LDS coherence across waves WITHOUT draining vmcnt.
// "memory" clobber + sched_barrier(0xF) block MEMORY-op motion across the
// barrier (cross-wave visibility) but ALLOW VALU/SALU/MFMA to be scheduled
// across — the compiler can overlap register-only work with phase boundaries.
// (Rule #18 hazard doesn't apply: all LDS reads here are compiler-visible
// loads, so read->use waits are auto-inserted.)
__device__ __forceinline__ void fast_barrier() {
  asm volatile("s_waitcnt lgkmcnt(0)" ::: "memory");
  __builtin_amdgcn_s_barrier();
  __builtin_amdgcn_sched_barrier(0xF);  // allow ALU|VALU|SALU|MFMA across
}

#define MFMA16(a, b, c) __builtin_amdgcn_mfma_f32_16x16x32_bf16((a), (b), (c), 0, 0, 0)

// B-fragment of W^T for out = in @ W.T, W row-major (N,K):
// lane holds W[rowbase + (lane&15)][kbase + 8*(lane>>4) + v], v=0..7
__device__ __forceinline__ bf16x8 load_wfrag(const float* __restrict__ W, int ldk,
                                             int rowbase, int kbase, int cl, int rg) {
  const float* p = W + (size_t)(rowbase + cl) * (size_t)ldk + (size_t)(kbase + rg * 8);
  float4 a = *reinterpret_cast<const float4*>(p);
  float4 b = *reinterpret_cast<const float4*>(p + 4);
  bf16x8 r;
  r[0] = (short)to_bf16u(a.x); r[1] = (short)to_bf16u(a.y);
  r[2] = (short)to_bf16u(a.z); r[3] = (short)to_bf16u(a.w);
  r[4] = (short)to_bf16u(b.x); r[5] = (short)to_bf16u(b.y);
  r[6] = (short)to_bf16u(b.z); r[7] = (short)to_bf16u(b.w);
  return r;
}

// A-fragment read from a bf16 [16][ROWB/2] LDS tile, XOR-swizzled 16B chunks.
template <int ROWB, int SLOTS>
__device__ __forceinline__ bf16x8 lds_afrag(const unsigned short* buf, int kt, int cl, int rg) {
  int chunk = (kt * 4 + rg) ^ (cl & (SLOTS - 1));
  return *reinterpret_cast<const bf16x8*>(
      reinterpret_cast<const char*>(buf) + cl * ROWB + chunk * 16);
}

// C-frag (col=lane&15, row=(lane>>4)*4+reg) -> bf16 LDS tile with matching swizzle
template <int ROWB, int SLOTS>
__device__ __forceinline__ void store_c_lds(unsigned short* buf, int colbase, f32x4 v,
                                            int cl, int rg) {
#pragma unroll
  for (int r = 0; r < 4; ++r) {
    int row = rg * 4 + r;
    int col = colbase + cl;
    int chunk = (col >> 3) ^ (row & (SLOTS - 1));
    *reinterpret_cast<unsigned short*>(
        reinterpret_cast<char*>(buf) + row * ROWB + chunk * 16 + (col & 7) * 2) =
        to_bf16u(v[r]);
  }
}

__device__ __forceinline__ void store_c_glb(float* __restrict__ base, int ld, int colbase,
                                            f32x4 v, int cl, int rg) {
#pragma unroll
  for (int r = 0; r < 4; ++r) base[(rg * 4 + r) * ld + colbase + cl] = v[r];
}

// packed-fragment LDS blocks: frag f at [f*512, +512) ushorts, lane-major (conflict-free)
__device__ __forceinline__ bf16x8 read_pfrag(const unsigned short* buf, int f, int lane) {
  return *reinterpret_cast<const bf16x8*>(buf + f * 512 + lane * 8);
}

// 8 waves/block, each owns 16 h-cols -> weight frags fit the 256-reg unified
// budget (VGPR+AGPR) at 2 waves/SIMD without spill (R4-verified).
__global__ __launch_bounds__(512, 2) void sinkbf_kernel(
    const float* __restrict__ Y0, const float* __restrict__ Wq, const float* __restrict__ bq,
    const float* __restrict__ Wp1, const float* __restrict__ bp1,
    const float* __restrict__ Wp2, const float* __restrict__ bp2,
    const float* __restrict__ Ww, const float* __restrict__ bw,
    const float* __restrict__ Wih0, const float* __restrict__ Whh0,
    const float* __restrict__ bih0, const float* __restrict__ bhh0,
    const float* __restrict__ Wih1, const float* __restrict__ Whh1,
    const float* __restrict__ bih1, const float* __restrict__ bhh1,
    float* __restrict__ outX, float* __restrict__ outW, float* __restrict__ outY) {
  const int tid = threadIdx.x;
  const int wid = tid >> 6;        // wave 0..7, owns h-cols [wid*16, wid*16+16)
  const int lane = tid & 63;
  const int cl = lane & 15;
  const int rg = lane >> 4;
  const int row0 = blockIdx.x * 16;  // batch tile
  const int c0 = wid * 16;

  __shared__ __align__(16) unsigned short sH0[2][16 * 128];
  __shared__ __align__(16) unsigned short sH1[2][16 * 128];
  __shared__ __align__(16) unsigned short sWb[16 * 64];
  __shared__ __align__(16) unsigned short sT[16 * 128];
  __shared__ __align__(16) unsigned short sYh[16 * 32];
  __shared__ __align__(16) unsigned short sWwP[20 * 512];
  __shared__ __align__(16) unsigned short sWp1P[32 * 512];
  __shared__ __align__(16) unsigned short sWp2P[8 * 512];

  const f32x4 vzero = {0.f, 0.f, 0.f, 0.f};

  // ---- persistent register-resident weight B-fragments (16 cols/wave) ----
  bf16x8 wI0[3][2];  // Wih0 (384,64)
  bf16x8 wH0[3][4];  // Whh0 (384,128)
  bf16x8 wI1[3][4];  // Wih1 (384,128)
  bf16x8 wH1[3][4];  // Whh1 (384,128)
#pragma unroll
  for (int g = 0; g < 3; ++g) {
    int rb = g * 128 + c0;
#pragma unroll
    for (int kt = 0; kt < 2; ++kt) wI0[g][kt] = load_wfrag(Wih0, 64, rb, kt * 32, cl, rg);
#pragma unroll
    for (int kt = 0; kt < 4; ++kt) wH0[g][kt] = load_wfrag(Whh0, 128, rb, kt * 32, cl, rg);
#pragma unroll
    for (int kt = 0; kt < 4; ++kt) wI1[g][kt] = load_wfrag(Wih1, 128, rb, kt * 32, cl, rg);
#pragma unroll
    for (int kt = 0; kt < 4; ++kt) wH1[g][kt] = load_wfrag(Whh1, 128, rb, kt * 32, cl, rg);
  }

  // ---- pack small weights to LDS as fragments ----
  if (wid < 4) {
#pragma unroll
    for (int kt = 0; kt < 5; ++kt) {  // Ww (64,160): waves 0-3 own w-cols [wid*16,+16)
      bf16x8 f = load_wfrag(Ww, 160, wid * 16, kt * 32, cl, rg);
      *reinterpret_cast<bf16x8*>(&sWwP[(wid * 5 + kt) * 512 + lane * 8]) = f;
    }
  }
#pragma unroll
  for (int kt = 0; kt < 4; ++kt) {  // Wp1 (128,128): each wave its 16 cols
    bf16x8 f = load_wfrag(Wp1, 128, c0, kt * 32, cl, rg);
    *reinterpret_cast<bf16x8*>(&sWp1P[(wid * 4 + kt) * 512 + lane * 8]) = f;
  }
  if (wid < 2) {
#pragma unroll
    for (int kt = 0; kt < 4; ++kt) {  // Wp2 (32,128): waves 0,1 own 16 y-cols
      bf16x8 f = load_wfrag(Wp2, 128, wid * 16, kt * 32, cl, rg);
      *reinterpret_cast<bf16x8*>(&sWp2P[(wid * 4 + kt) * 512 + lane * 8]) = f;
    }
  }

  // ---- per-lane biases (fp32) ----
  const int c = c0 + cl;
  const float b0r = bih0[c] + bhh0[c];
  const float b0z = bih0[128 + c] + bhh0[128 + c];
  const float b0in = bih0[256 + c];
  const float b0hn = bhh0[256 + c];
  const float b1r = bih1[c] + bhh1[c];
  const float b1z = bih1[128 + c] + bhh1[128 + c];
  const float b1in = bih1[256 + c];
  const float b1hn = bhh1[256 + c];
  const float bp1l = bp1[c];
  const float bwl = bw[(wid & 3) * 16 + cl];
  const float bp2l = (wid < 2) ? bp2[wid * 16 + cl] : 0.f;

  f32x4 hp0, hp1;  // fp32 master copy of this wave's own h columns

  // ---- init: x0 = tanh(Y0[0] @ Wq.T + bq) ----
  {
    bf16x8 aY = load_wfrag(Y0, 32, row0, 0, cl, rg);
    bf16x8 q0 = load_wfrag(Wq, 32, c0, 0, cl, rg);
    bf16x8 q1 = load_wfrag(Wq, 32, 128 + c0, 0, cl, rg);
    float bq0v = bq[c];
    float bq1v = bq[128 + c];
    f32x4 acc = MFMA16(aY, q0, vzero);
#pragma unroll
    for (int r = 0; r < 4; ++r) hp0[r] = ftanh(acc[r] + bq0v);
    store_c_lds<256, 8>(sH0[0], c0, hp0, cl, rg);
    acc = MFMA16(aY, q1, vzero);
#pragma unroll
    for (int r = 0; r < 4; ++r) hp1[r] = ftanh(acc[r] + bq1v);
    store_c_lds<256, 8>(sH1[0], c0, hp1, cl, rg);
    store_c_glb(outX + (size_t)row0 * 128, 128, c0, hp1, cl, rg);  // X[0]
  }
  __syncthreads();

  // ---- Y0 prefetch registers (one step ahead; waves 0-3 only) ----
  float4 yA, yB;
  if (wid < 4) {
    const float* py = Y0 + (size_t)1 * (NBATCH * 32) + (size_t)(row0 + cl) * 32 + rg * 8;
    yA = *reinterpret_cast<const float4*>(py);
    yB = *reinterpret_cast<const float4*>(py + 4);
  }

  // carried output pointers (strength-reduced addressing)
  float* pX = outX + (size_t)(NBATCH * 128) + (size_t)row0 * 128;  // X[1+t]
  float* pW = outW + (size_t)row0 * 64;                            // W[t]
  float* pY = outY + (size_t)row0 * 32;                            // Yhat[t]

  // ---- P phase: t = tanh(h1@Wp1.T+bp1); yhat = t@Wp2.T+bp2 (warmup only) ----
  auto p_phase = [&](float* yout, const unsigned short* h1buf) {
    bf16x8 a1[4];
#pragma unroll
    for (int kt = 0; kt < 4; ++kt) a1[kt] = lds_afrag<256, 8>(h1buf, kt, cl, rg);
    f32x4 acc = vzero;
#pragma unroll
    for (int kt = 0; kt < 4; ++kt)
      acc = MFMA16(a1[kt], read_pfrag(sWp1P, wid * 4 + kt, lane), acc);
    f32x4 tv;
#pragma unroll
    for (int r = 0; r < 4; ++r) tv[r] = ftanh(acc[r] + bp1l);
    store_c_lds<256, 8>(sT, c0, tv, cl, rg);
    fast_barrier();
    if (wid < 2) {
      bf16x8 at[4];
#pragma unroll
      for (int kt = 0; kt < 4; ++kt) at[kt] = lds_afrag<256, 8>(sT, kt, cl, rg);
      f32x4 acc2 = vzero;
#pragma unroll
      for (int kt = 0; kt < 4; ++kt) acc2 = MFMA16(at[kt], read_pfrag(sWp2P, wid * 4 + kt, lane), acc2);
      f32x4 y;
#pragma unroll
      for (int r = 0; r < 4; ++r) y[r] = acc2[r] + bp2l;
      store_c_glb(yout, 32, wid * 16, y, cl, rg);
      store_c_lds<64, 4>(sYh, wid * 16, y, cl, rg);
    }
    fast_barrier();
  };

  p_phase(pY, sH1[0]);  // yhat0
  pY += NBATCH * 32;

  // ======================= main scan =======================
#pragma unroll 1
  for (int t = 0; t < TSTEPS; ++t) {
    const int cur = t & 1, nxt = cur ^ 1;
    const unsigned short* h0c = sH0[cur];
    unsigned short* h0w = sH0[nxt];
    const unsigned short* h1c = sH1[cur];
    unsigned short* h1w = sH1[nxt];
    const bool warm = (t < NWUPC);

    // step-top reads of STABLE double-buffered state (written before last
    // barrier of previous step) — compiler may overlap these with anything.
    bf16x8 aH0[4], aH1[4];
#pragma unroll
    for (int kt = 0; kt < 4; ++kt) aH0[kt] = lds_afrag<256, 8>(h0c, kt, cl, rg);
#pragma unroll
    for (int kt = 0; kt < 4; ++kt) aH1[kt] = lds_afrag<256, 8>(h1c, kt, cl, rg);

    // ---- W phase (warmup only; else w==0 so gi0 = bias) ----
    if (warm) {
      if (wid < 4) {
        bf16x8 ae;  // e = Y0[1+t] - yhat
        {
          int chunk = rg ^ (cl & 3);
          bf16x8 yh = *reinterpret_cast<const bf16x8*>(
              reinterpret_cast<const char*>(sYh) + cl * 64 + chunk * 16);  // stable
          ae[0] = (short)to_bf16u(yA.x - bf16_to_f(yh[0]));
          ae[1] = (short)to_bf16u(yA.y - bf16_to_f(yh[1]));
          ae[2] = (short)to_bf16u(yA.z - bf16_to_f(yh[2]));
          ae[3] = (short)to_bf16u(yA.w - bf16_to_f(yh[3]));
          ae[4] = (short)to_bf16u(yB.x - bf16_to_f(yh[4]));
          ae[5] = (short)to_bf16u(yB.y - bf16_to_f(yh[5]));
          ae[6] = (short)to_bf16u(yB.z - bf16_to_f(yh[6]));
          ae[7] = (short)to_bf16u(yB.w - bf16_to_f(yh[7]));
        }
        if (t + 1 < NWUPC) {  // prefetch next y — stays in flight across barriers
          const float* py = Y0 + (size_t)(2 + t) * (NBATCH * 32) + (size_t)(row0 + cl) * 32 + rg * 8;
          yA = *reinterpret_cast<const float4*>(py);
          yB = *reinterpret_cast<const float4*>(py + 4);
        }
        f32x4 acc = vzero;
#pragma unroll
        for (int kt = 0; kt < 4; ++kt)
          acc = MFMA16(aH0[kt], read_pfrag(sWwP, wid * 5 + kt, lane), acc);
        acc = MFMA16(ae, read_pfrag(sWwP, wid * 5 + 4, lane), acc);
        f32x4 wv;
#pragma unroll
        for (int r = 0; r < 4; ++r) wv[r] = ftanh(acc[r] + bwl);
        store_c_lds<128, 8>(sWb, wid * 16, wv, cl, rg);
        store_c_glb(pW, 64, wid * 16, wv, cl, rg);
      }
      fast_barrier();  // sWb visible to all waves
    }

    // ---- layer 0 ----
    f32x4 ar0i = vzero, az0i = vzero, ain0 = vzero;
    if (warm) {
      bf16x8 aw0 = lds_afrag<128, 8>(sWb, 0, cl, rg);
      bf16x8 aw1 = lds_afrag<128, 8>(sWb, 1, cl, rg);
      ar0i = MFMA16(aw0, wI0[0][0], ar0i);  ar0i = MFMA16(aw1, wI0[0][1], ar0i);
      az0i = MFMA16(aw0, wI0[1][0], az0i);  az0i = MFMA16(aw1, wI0[1][1], az0i);
      ain0 = MFMA16(aw0, wI0[2][0], ain0);  ain0 = MFMA16(aw1, wI0[2][1], ain0);
    }
    f32x4 ar0h = vzero, az0h = vzero, ahn0 = vzero;
#pragma unroll
    for (int kt = 0; kt < 4; ++kt) {
      ar0h = MFMA16(aH0[kt], wH0[0][kt], ar0h);
      az0h = MFMA16(aH0[kt], wH0[1][kt], az0h);
      ahn0 = MFMA16(aH0[kt], wH0[2][kt], ahn0);
    }
    f32x4 h0new;
#pragma unroll
    for (int r = 0; r < 4; ++r) {
      float rr = sigm(ar0i[r] + ar0h[r] + b0r);
      float zz = sigm(az0i[r] + az0h[r] + b0z);
      float ng = ftanh(ain0[r] + b0in + rr * (ahn0[r] + b0hn));
      h0new[r] = (1.f - zz) * ng + zz * hp0[r];
    }
    store_c_lds<256, 8>(h0w, c0, h0new, cl, rg);
    hp0 = h0new;
    fast_barrier();  // h0_new visible

    // ---- layer 1: gi1(A=h0_new fresh) + gh1(A=h1_prev hoisted), split chains ----
    bf16x8 aH0n[4];
#pragma unroll
    for (int kt = 0; kt < 4; ++kt) aH0n[kt] = lds_afrag<256, 8>(h0w, kt, cl, rg);
    f32x4 ar1i = vzero, az1i = vzero, ain1 = vzero;
    f32x4 ar1h = vzero, az1h = vzero, ahn1 = vzero;
#pragma unroll
    for (int kt = 0; kt < 4; ++kt) {
      ar1h = MFMA16(aH1[kt], wH1[0][kt], ar1h);
      az1h = MFMA16(aH1[kt], wH1[1][kt], az1h);
      ahn1 = MFMA16(aH1[kt], wH1[2][kt], ahn1);
      ar1i = MFMA16(aH0n[kt], wI1[0][kt], ar1i);
      az1i = MFMA16(aH0n[kt], wI1[1][kt], az1i);
      ain1 = MFMA16(aH0n[kt], wI1[2][kt], ain1);
    }
    f32x4 h1new;
#pragma unroll
    for (int r = 0; r < 4; ++r) {
      float rr = sigm(ar1i[r] + ar1h[r] + b1r);
      float zz = sigm(az1i[r] + az1h[r] + b1z);
      float ng = ftanh(ain1[r] + b1in + rr * (ahn1[r] + b1hn));
      h1new[r] = (1.f - zz) * ng + zz * hp1[r];
    }
    store_c_lds<256, 8>(h1w, c0, h1new, cl, rg);
    store_c_glb(pX, 128, c0, h1new, cl, rg);
    hp1 = h1new;
    fast_barrier();  // h1_new visible

    if (warm) {
      p_phase(pY, h1w);  // yhat needed only while e feeds back
    }

    pX += NBATCH * 128;
    pW += NBATCH * 64;
    pY += NBATCH * 32;
  }
}

// Horizon Yhat: Yhat[tt] = tanh(X[tt]@Wp1.T+bp1)@Wp2.T+bp2, tt in [257,512].
// Fully parallel over (tt, batch); bitwise-matches the inline P path.
__global__ __launch_bounds__(256, 1) void yhat_hrzn_kernel(
    const float* __restrict__ X, const float* __restrict__ Wp1, const float* __restrict__ bp1,
    const float* __restrict__ Wp2, const float* __restrict__ bp2, float* __restrict__ outY) {
  const int tid = threadIdx.x;
  const int wid = tid >> 6;
  const int lane = tid & 63;
  const int cl = lane & 15;
  const int rg = lane >> 4;
  const int tile = blockIdx.x & 63;       // batch tile
  const int tg = blockIdx.x >> 6;         // time group, 4 steps each
  const int row0 = tile * 16;
  const int c0 = wid * 32;

  __shared__ __align__(16) unsigned short sT2[2][16 * 128];
  const f32x4 vzero = {0.f, 0.f, 0.f, 0.f};

  bf16x8 wp1f[2][4];
#pragma unroll
  for (int tl = 0; tl < 2; ++tl)
#pragma unroll
    for (int kt = 0; kt < 4; ++kt) wp1f[tl][kt] = load_wfrag(Wp1, 128, c0 + tl * 16, kt * 32, cl, rg);
  bf16x8 wp2f[4];
  if (wid < 2) {
#pragma unroll
    for (int kt = 0; kt < 4; ++kt) wp2f[kt] = load_wfrag(Wp2, 128, wid * 16, kt * 32, cl, rg);
  } else {
#pragma unroll
    for (int kt = 0; kt < 4; ++kt) wp2f[kt] = bf16x8{0, 0, 0, 0, 0, 0, 0, 0};
  }
  float bp1l[2] = {bp1[c0 + cl], bp1[c0 + 16 + cl]};
  const float bp2l = (wid < 2) ? bp2[wid * 16 + cl] : 0.f;

#pragma unroll 1
  for (int i = 0; i < 4; ++i) {
    const int tt = 257 + tg * 4 + i;
    const float* xb = X + (size_t)tt * (NBATCH * 128);
    bf16x8 aX[4];
#pragma unroll
    for (int kt = 0; kt < 4; ++kt) aX[kt] = load_wfrag(xb, 128, row0, kt * 32, cl, rg);
#pragma unroll
    for (int tl = 0; tl < 2; ++tl) {
      f32x4 acc = vzero;
#pragma unroll
      for (int kt = 0; kt < 4; ++kt) acc = MFMA16(aX[kt], wp1f[tl][kt], acc);
      f32x4 tv;
#pragma unroll
      for (int r = 0; r < 4; ++r) tv[r] = ftanh(acc[r] + bp1l[tl]);
      store_c_lds<256, 8>(sT2[i & 1], c0 + tl * 16, tv, cl, rg);
    }
    __syncthreads();
    if (wid < 2) {
      bf16x8 at[4];
#pragma unroll
      for (int kt = 0; kt < 4; ++kt) at[kt] = lds_afrag<256, 8>(sT2[i & 1], kt, cl, rg);
      f32x4 acc = vzero;
#pragma unroll
      for (int kt = 0; kt < 4; ++kt) acc = MFMA16(at[kt], wp2f[kt], acc);
      f32x4 y;
#pragma unroll
      for (int r = 0; r < 4; ++r) y[r] = acc[r] + bp2l;
      store_c_glb(outY + (size_t)tt * (NBATCH * 32) + (size_t)row0 * 32, 32, wid * 16, y, cl, rg);
    }
  }
}

extern "C" void kernel_launch(void* const* d_in, const int* in_sizes, int n_in,
                              void* d_out, int out_size, void* d_ws, size_t ws_size,
                              hipStream_t stream) {
  (void)in_sizes; (void)n_in; (void)out_size; (void)d_ws; (void)ws_size;
  const float* Y0   = (const float*)d_in[0];
  const float* Wq   = (const float*)d_in[1];
  const float* bq   = (const float*)d_in[2];
  const float* Wp1  = (const float*)d_in[3];
  const float* bp1  = (const float*)d_in[4];
  const float* Wp2  = (const float*)d_in[5];
  const float* bp2  = (const float*)d_in[6];
  const float* Ww   = (const float*)d_in[7];
  const float* bw   = (const float*)d_in[8];
  const float* Wih0 = (const float*)d_in[9];
  const float* Whh0 = (const float*)d_in[10];
  const float* bih0 = (const float*)d_in[11];
  const float* bhh0 = (const float*)d_in[12];
  const float* Wih1 = (const float*)d_in[13];
  const float* Whh1 = (const float*)d_in[14];
  const float* bih1 = (const float*)d_in[15];
  const float* bhh1 = (const float*)d_in[16];

  float* outX = (float*)d_out;
  float* outW = outX + XLEN;
  float* outY = outW + WLEN;

  sinkbf_kernel<<<dim3(NBATCH / 16), dim3(512), 0, stream>>>(
      Y0, Wq, bq, Wp1, bp1, Wp2, bp2, Ww, bw,
      Wih0, Whh0, bih0, bhh0, Wih1, Whh1, bih1, bhh1,
      outX, outW, outY);

  // horizon Yhat from streamed X (same stream -> ordered after main kernel)
  yhat_hrzn_kernel<<<dim3(64 * 64), dim3(256), 0, stream>>>(
      outX, Wp1, bp1, Wp2, bp2, outY);
}

// Round 7
// 1850.923 us; speedup vs baseline: 1.1919x; 1.1919x over previous
//
#include <hip/hip_runtime.h>

// Fixed problem dims: NX=128, NW=64, NY=32, NLAYER=2, NWUP=256, NBATCH=1024, NHRZN=256
#define NBATCH 1024
#define TSTEPS 512
#define NWUPC  256

// Output layout in d_out (fp32, flat, concatenated in return order):
//   X    (513,1024,128) : 67239936
//   W    (256,1024, 64) : 16777216
//   Yhat (513,1024, 32) : 16809984
#define XLEN 67239936ULL
#define WLEN 16777216ULL

typedef __attribute__((ext_vector_type(8))) short bf16x8;  // 8 bf16 in 4 VGPRs
typedef __attribute__((ext_vector_type(4))) float f32x4;   // MFMA 16x16 C/D

__device__ __forceinline__ unsigned short to_bf16u(float f) {
  union { float f; unsigned u; } v; v.f = f;
  unsigned r = (v.u + 0x7FFFu + ((v.u >> 16) & 1u)) >> 16;  // RNE (init-time paths)
  return (unsigned short)r;
}
__device__ __forceinline__ float bf16_to_f(short h) {
  union { unsigned u; float f; } v;
  v.u = ((unsigned)(unsigned short)h) << 16;
  return v.f;
}
// HW packed f32->bf16 (RNE); no builtin on gfx950 -> inline asm (T12/m240).
__device__ __forceinline__ unsigned cvt_pk_bf16(float lo, float hi) {
  unsigned r;
  asm("v_cvt_pk_bf16_f32 %0, %1, %2" : "=v"(r) : "v"(lo), "v"(hi));
  return r;
}
// clampless: |u| <~ 10 by weight scale (0.05) and bounded h; exp safe to ~88.
// (R6 ran clampless with identical absmax 4.88e-3.)
__device__ __forceinline__ float ftanh(float x) {
  float e = __expf(2.f * x);
  return (e - 1.f) * __builtin_amdgcn_rcpf(e + 1.f);
}

// lgkmcnt-only barrier (R4 form — do not relax; R6 proved 0xF regresses).
__device__ __forceinline__ void fast_barrier() {
  __builtin_amdgcn_sched_barrier(0);
  asm volatile("s_waitcnt lgkmcnt(0)" ::: "memory");
  __builtin_amdgcn_s_barrier();
  __builtin_amdgcn_sched_barrier(0);
}

#define MFMA16(a, b, c) __builtin_amdgcn_mfma_f32_16x16x32_bf16((a), (b), (c), 0, 0, 0)

// B-fragment of W^T for out = in @ W.T, W row-major (N,K):
// lane holds W[rowbase + (lane&15)][kbase + 8*(lane>>4) + v], v=0..7
__device__ __forceinline__ bf16x8 load_wfrag(const float* __restrict__ W, int ldk,
                                             int rowbase, int kbase, int cl, int rg) {
  const float* p = W + (size_t)(rowbase + cl) * (size_t)ldk + (size_t)(kbase + rg * 8);
  float4 a = *reinterpret_cast<const float4*>(p);
  float4 b = *reinterpret_cast<const float4*>(p + 4);
  bf16x8 r;
  r[0] = (short)to_bf16u(a.x); r[1] = (short)to_bf16u(a.y);
  r[2] = (short)to_bf16u(a.z); r[3] = (short)to_bf16u(a.w);
  r[4] = (short)to_bf16u(b.x); r[5] = (short)to_bf16u(b.y);
  r[6] = (short)to_bf16u(b.z); r[7] = (short)to_bf16u(b.w);
  return r;
}

// A-fragment read from a bf16 [16][ROWB/2] LDS tile, XOR-swizzled 16B chunks.
template <int ROWB, int SLOTS>
__device__ __forceinline__ bf16x8 lds_afrag(const unsigned short* buf, int kt, int cl, int rg) {
  int chunk = (kt * 4 + rg) ^ (cl & (SLOTS - 1));
  return *reinterpret_cast<const bf16x8*>(
      reinterpret_cast<const char*>(buf) + cl * ROWB + chunk * 16);
}

// C-frag (col=lane&15, row=(lane>>4)*4+reg) -> bf16 LDS tile, matching swizzle.
// cvt_pk packs pairs in 2 ops (vs 16 hand-RNE ops).
template <int ROWB, int SLOTS>
__device__ __forceinline__ void store_c_lds(unsigned short* buf, int colbase, f32x4 v,
                                            int cl, int rg) {
  unsigned p01 = cvt_pk_bf16(v[0], v[1]);
  unsigned p23 = cvt_pk_bf16(v[2], v[3]);
  unsigned hh[4] = {p01, p01 >> 16, p23, p23 >> 16};
  int col = colbase + cl;
#pragma unroll
  for (int r = 0; r < 4; ++r) {
    int row = rg * 4 + r;
    int chunk = (col >> 3) ^ (row & (SLOTS - 1));
    *reinterpret_cast<unsigned short*>(
        reinterpret_cast<char*>(buf) + row * ROWB + chunk * 16 + (col & 7) * 2) =
        (unsigned short)hh[r];
  }
}

__device__ __forceinline__ void store_c_glb(float* __restrict__ base, int ld, int colbase,
                                            f32x4 v, int cl, int rg) {
#pragma unroll
  for (int r = 0; r < 4; ++r) base[(rg * 4 + r) * ld + colbase + cl] = v[r];
}

// packed-fragment LDS blocks: frag f at [f*512, +512) ushorts, lane-major (conflict-free)
__device__ __forceinline__ bf16x8 read_pfrag(const unsigned short* buf, int f, int lane) {
  return *reinterpret_cast<const bf16x8*>(buf + f * 512 + lane * 8);
}

// 8 waves/block, each owns 16 h-cols -> weight frags fit the 256-reg unified
// budget (VGPR+AGPR) at 2 waves/SIMD without spill (R4-verified).
__global__ __launch_bounds__(512, 2) void sinkbf_kernel(
    const float* __restrict__ Y0, const float* __restrict__ Wq, const float* __restrict__ bq,
    const float* __restrict__ Wp1, const float* __restrict__ bp1,
    const float* __restrict__ Wp2, const float* __restrict__ bp2,
    const float* __restrict__ Ww, const float* __restrict__ bw,
    const float* __restrict__ Wih0, const float* __restrict__ Whh0,
    const float* __restrict__ bih0, const float* __restrict__ bhh0,
    const float* __restrict__ Wih1, const float* __restrict__ Whh1,
    const float* __restrict__ bih1, const float* __restrict__ bhh1,
    float* __restrict__ outX, float* __restrict__ outW, float* __restrict__ outY) {
  const int tid = threadIdx.x;
  const int wid = tid >> 6;        // wave 0..7, owns h-cols [wid*16, wid*16+16)
  const int lane = tid & 63;
  const int cl = lane & 15;
  const int rg = lane >> 4;
  const int row0 = blockIdx.x * 16;  // batch tile
  const int c0 = wid * 16;

  __shared__ __align__(16) unsigned short sH0[2][16 * 128];
  __shared__ __align__(16) unsigned short sH1[2][16 * 128];
  __shared__ __align__(16) unsigned short sWb[16 * 64];
  __shared__ __align__(16) unsigned short sT[16 * 128];
  __shared__ __align__(16) unsigned short sYh[16 * 32];
  __shared__ __align__(16) unsigned short sWwP[20 * 512];
  __shared__ __align__(16) unsigned short sWp1P[32 * 512];
  __shared__ __align__(16) unsigned short sWp2P[8 * 512];

  const f32x4 vzero = {0.f, 0.f, 0.f, 0.f};

  // ---- persistent register-resident weight B-fragments (16 cols/wave) ----
  bf16x8 wI0[3][2];  // Wih0 (384,64)
  bf16x8 wH0[3][4];  // Whh0 (384,128)
  bf16x8 wI1[3][4];  // Wih1 (384,128)
  bf16x8 wH1[3][4];  // Whh1 (384,128)
#pragma unroll
  for (int g = 0; g < 3; ++g) {
    int rb = g * 128 + c0;
#pragma unroll
    for (int kt = 0; kt < 2; ++kt) wI0[g][kt] = load_wfrag(Wih0, 64, rb, kt * 32, cl, rg);
#pragma unroll
    for (int kt = 0; kt < 4; ++kt) wH0[g][kt] = load_wfrag(Whh0, 128, rb, kt * 32, cl, rg);
#pragma unroll
    for (int kt = 0; kt < 4; ++kt) wI1[g][kt] = load_wfrag(Wih1, 128, rb, kt * 32, cl, rg);
#pragma unroll
    for (int kt = 0; kt < 4; ++kt) wH1[g][kt] = load_wfrag(Whh1, 128, rb, kt * 32, cl, rg);
  }

  // ---- pack small weights to LDS as fragments ----
  if (wid < 4) {
#pragma unroll
    for (int kt = 0; kt < 5; ++kt) {  // Ww (64,160): waves 0-3 own w-cols [wid*16,+16)
      bf16x8 f = load_wfrag(Ww, 160, wid * 16, kt * 32, cl, rg);
      *reinterpret_cast<bf16x8*>(&sWwP[(wid * 5 + kt) * 512 + lane * 8]) = f;
    }
  }
#pragma unroll
  for (int kt = 0; kt < 4; ++kt) {  // Wp1 (128,128): each wave its 16 cols
    bf16x8 f = load_wfrag(Wp1, 128, c0, kt * 32, cl, rg);
    *reinterpret_cast<bf16x8*>(&sWp1P[(wid * 4 + kt) * 512 + lane * 8]) = f;
  }
  if (wid < 2) {
#pragma unroll
    for (int kt = 0; kt < 4; ++kt) {  // Wp2 (32,128): waves 0,1 own 16 y-cols
      bf16x8 f = load_wfrag(Wp2, 128, wid * 16, kt * 32, cl, rg);
      *reinterpret_cast<bf16x8*>(&sWp2P[(wid * 4 + kt) * 512 + lane * 8]) = f;
    }
  }

  // ---- per-lane biases (fp32) ----
  const int c = c0 + cl;
  const float b0r = bih0[c] + bhh0[c];
  const float b0z = bih0[128 + c] + bhh0[128 + c];
  const float b0in = bih0[256 + c];
  const float b0hn = bhh0[256 + c];
  const float b1r = bih1[c] + bhh1[c];
  const float b1z = bih1[128 + c] + bhh1[128 + c];
  const float b1in = bih1[256 + c];
  const float b1hn = bhh1[256 + c];
  const float bp1l = bp1[c];
  const float bwl = bw[(wid & 3) * 16 + cl];
  const float bp2l = (wid < 2) ? bp2[wid * 16 + cl] : 0.f;

  f32x4 hp0, hp1;  // fp32 master copy of this wave's own h columns

  // ---- init: x0 = tanh(Y0[0] @ Wq.T + bq) ----
  {
    bf16x8 aY = load_wfrag(Y0, 32, row0, 0, cl, rg);
    bf16x8 q0 = load_wfrag(Wq, 32, c0, 0, cl, rg);
    bf16x8 q1 = load_wfrag(Wq, 32, 128 + c0, 0, cl, rg);
    float bq0v = bq[c];
    float bq1v = bq[128 + c];
    f32x4 acc = MFMA16(aY, q0, vzero);
#pragma unroll
    for (int r = 0; r < 4; ++r) hp0[r] = ftanh(acc[r] + bq0v);
    store_c_lds<256, 8>(sH0[0], c0, hp0, cl, rg);
    acc = MFMA16(aY, q1, vzero);
#pragma unroll
    for (int r = 0; r < 4; ++r) hp1[r] = ftanh(acc[r] + bq1v);
    store_c_lds<256, 8>(sH1[0], c0, hp1, cl, rg);
    store_c_glb(outX + (size_t)row0 * 128, 128, c0, hp1, cl, rg);  // X[0]
  }
  __syncthreads();

  // ---- Y0 prefetch registers (one step ahead; waves 0-3 only) ----
  float4 yA, yB;
  if (wid < 4) {
    const float* py = Y0 + (size_t)1 * (NBATCH * 32) + (size_t)(row0 + cl) * 32 + rg * 8;
    yA = *reinterpret_cast<const float4*>(py);
    yB = *reinterpret_cast<const float4*>(py + 4);
  }

  // carried output pointers (strength-reduced addressing)
  float* pX = outX + (size_t)(NBATCH * 128) + (size_t)row0 * 128;  // X[1+t]
  float* pW = outW + (size_t)row0 * 64;                            // W[t]
  float* pY = outY + (size_t)row0 * 32;                            // Yhat[t]

  // ---- P phase: t = tanh(h1@Wp1.T+bp1); yhat = t@Wp2.T+bp2 (warmup only) ----
  auto p_phase = [&](float* yout, const unsigned short* h1buf) {
    bf16x8 a1[4];
#pragma unroll
    for (int kt = 0; kt < 4; ++kt) a1[kt] = lds_afrag<256, 8>(h1buf, kt, cl, rg);
    f32x4 acc = vzero;
#pragma unroll
    for (int kt = 0; kt < 4; ++kt)
      acc = MFMA16(a1[kt], read_pfrag(sWp1P, wid * 4 + kt, lane), acc);
    f32x4 tv;
#pragma unroll
    for (int r = 0; r < 4; ++r) tv[r] = ftanh(acc[r] + bp1l);
    store_c_lds<256, 8>(sT, c0, tv, cl, rg);
    fast_barrier();
    if (wid < 2) {
      bf16x8 at[4];
#pragma unroll
      for (int kt = 0; kt < 4; ++kt) at[kt] = lds_afrag<256, 8>(sT, kt, cl, rg);
      f32x4 acc2 = vzero;
#pragma unroll
      for (int kt = 0; kt < 4; ++kt) acc2 = MFMA16(at[kt], read_pfrag(sWp2P, wid * 4 + kt, lane), acc2);
      f32x4 y;
#pragma unroll
      for (int r = 0; r < 4; ++r) y[r] = acc2[r] + bp2l;
      store_c_glb(yout, 32, wid * 16, y, cl, rg);
      store_c_lds<64, 4>(sYh, wid * 16, y, cl, rg);
    }
    fast_barrier();
  };

  p_phase(pY, sH1[0]);  // yhat0
  pY += NBATCH * 32;

  // ======================= main scan =======================
#pragma unroll 1
  for (int t = 0; t < TSTEPS; ++t) {
    const int cur = t & 1, nxt = cur ^ 1;
    const unsigned short* h0c = sH0[cur];
    unsigned short* h0w = sH0[nxt];
    const unsigned short* h1c = sH1[cur];
    unsigned short* h1w = sH1[nxt];
    const bool warm = (t < NWUPC);

    bf16x8 aH0[4];
#pragma unroll
    for (int kt = 0; kt < 4; ++kt) aH0[kt] = lds_afrag<256, 8>(h0c, kt, cl, rg);

    // ---- W phase (warmup only; else w==0 so gi0 = bias) ----
    if (warm) {
      if (wid < 4) {
        bf16x8 ae;  // e = Y0[1+t] - yhat
        {
          int chunk = rg ^ (cl & 3);
          bf16x8 yh = *reinterpret_cast<const bf16x8*>(
              reinterpret_cast<const char*>(sYh) + cl * 64 + chunk * 16);
          union { bf16x8 v; uint4 u; } aeu;
          aeu.u.x = cvt_pk_bf16(yA.x - bf16_to_f(yh[0]), yA.y - bf16_to_f(yh[1]));
          aeu.u.y = cvt_pk_bf16(yA.z - bf16_to_f(yh[2]), yA.w - bf16_to_f(yh[3]));
          aeu.u.z = cvt_pk_bf16(yB.x - bf16_to_f(yh[4]), yB.y - bf16_to_f(yh[5]));
          aeu.u.w = cvt_pk_bf16(yB.z - bf16_to_f(yh[6]), yB.w - bf16_to_f(yh[7]));
          ae = aeu.v;
        }
        if (t + 1 < NWUPC) {  // prefetch next y — stays in flight across barriers
          const float* py = Y0 + (size_t)(2 + t) * (NBATCH * 32) + (size_t)(row0 + cl) * 32 + rg * 8;
          yA = *reinterpret_cast<const float4*>(py);
          yB = *reinterpret_cast<const float4*>(py + 4);
        }
        f32x4 acc = vzero;
#pragma unroll
        for (int kt = 0; kt < 4; ++kt)
          acc = MFMA16(aH0[kt], read_pfrag(sWwP, wid * 5 + kt, lane), acc);
        acc = MFMA16(ae, read_pfrag(sWwP, wid * 5 + 4, lane), acc);
        f32x4 wv;
#pragma unroll
        for (int r = 0; r < 4; ++r) wv[r] = ftanh(acc[r] + bwl);
        store_c_lds<128, 8>(sWb, wid * 16, wv, cl, rg);
        store_c_glb(pW, 64, wid * 16, wv, cl, rg);
      }
      fast_barrier();  // sWb visible to all waves
    }

    // ---- layer 0 ----
    f32x4 ar0i = vzero, az0i = vzero, ain0 = vzero;
    if (warm) {
      bf16x8 aw0 = lds_afrag<128, 8>(sWb, 0, cl, rg);
      bf16x8 aw1 = lds_afrag<128, 8>(sWb, 1, cl, rg);
      ar0i = MFMA16(aw0, wI0[0][0], ar0i);  ar0i = MFMA16(aw1, wI0[0][1], ar0i);
      az0i = MFMA16(aw0, wI0[1][0], az0i);  az0i = MFMA16(aw1, wI0[1][1], az0i);
      ain0 = MFMA16(aw0, wI0[2][0], ain0);  ain0 = MFMA16(aw1, wI0[2][1], ain0);
    }
    f32x4 ar0h = vzero, az0h = vzero, ahn0 = vzero;
#pragma unroll
    for (int kt = 0; kt < 4; ++kt) {
      ar0h = MFMA16(aH0[kt], wH0[0][kt], ar0h);
      az0h = MFMA16(aH0[kt], wH0[1][kt], az0h);
      ahn0 = MFMA16(aH0[kt], wH0[2][kt], ahn0);
    }
    f32x4 h0new;
#pragma unroll
    for (int r = 0; r < 4; ++r) {
      float ur = ar0i[r] + ar0h[r] + b0r;
      float uz = az0i[r] + az0h[r] + b0z;
      float rr = __builtin_amdgcn_rcpf(1.f + __expf(-ur));
      float s  = __builtin_amdgcn_rcpf(1.f + __expf(uz));   // s = 1 - z
      float ng = ftanh(ain0[r] + b0in + rr * (ahn0[r] + b0hn));
      h0new[r] = hp0[r] + s * (ng - hp0[r]);
    }
    store_c_lds<256, 8>(h0w, c0, h0new, cl, rg);
    hp0 = h0new;
    fast_barrier();  // h0_new visible

    // ---- layer 1: gi1(A=h0_new) + gh1(A=h1_prev) ----
    bf16x8 aH0n[4], aH1[4];
#pragma unroll
    for (int kt = 0; kt < 4; ++kt) aH0n[kt] = lds_afrag<256, 8>(h0w, kt, cl, rg);
#pragma unroll
    for (int kt = 0; kt < 4; ++kt) aH1[kt] = lds_afrag<256, 8>(h1c, kt, cl, rg);
    f32x4 ar1i = vzero, az1i = vzero, ain1 = vzero;
    f32x4 ar1h = vzero, az1h = vzero, ahn1 = vzero;
#pragma unroll
    for (int kt = 0; kt < 4; ++kt) {
      ar1i = MFMA16(aH0n[kt], wI1[0][kt], ar1i);
      az1i = MFMA16(aH0n[kt], wI1[1][kt], az1i);
      ain1 = MFMA16(aH0n[kt], wI1[2][kt], ain1);
      ar1h = MFMA16(aH1[kt], wH1[0][kt], ar1h);
      az1h = MFMA16(aH1[kt], wH1[1][kt], az1h);
      ahn1 = MFMA16(aH1[kt], wH1[2][kt], ahn1);
    }
    f32x4 h1new;
#pragma unroll
    for (int r = 0; r < 4; ++r) {
      float ur = ar1i[r] + ar1h[r] + b1r;
      float uz = az1i[r] + az1h[r] + b1z;
      float rr = __builtin_amdgcn_rcpf(1.f + __expf(-ur));
      float s  = __builtin_amdgcn_rcpf(1.f + __expf(uz));   // s = 1 - z
      float ng = ftanh(ain1[r] + b1in + rr * (ahn1[r] + b1hn));
      h1new[r] = hp1[r] + s * (ng - hp1[r]);
    }
    store_c_lds<256, 8>(h1w, c0, h1new, cl, rg);
    store_c_glb(pX, 128, c0, h1new, cl, rg);
    hp1 = h1new;
    fast_barrier();  // h1_new visible

    if (warm) {
      p_phase(pY, h1w);  // yhat needed only while e feeds back
    }

    pX += NBATCH * 128;
    pW += NBATCH * 64;
    pY += NBATCH * 32;
  }
}

// Horizon Yhat: Yhat[tt] = tanh(X[tt]@Wp1.T+bp1)@Wp2.T+bp2, tt in [257,512].
// Fully parallel over (tt, batch); same math/rounding as the inline P path.
__global__ __launch_bounds__(256, 1) void yhat_hrzn_kernel(
    const float* __restrict__ X, const float* __restrict__ Wp1, const float* __restrict__ bp1,
    const float* __restrict__ Wp2, const float* __restrict__ bp2, float* __restrict__ outY) {
  const int tid = threadIdx.x;
  const int wid = tid >> 6;
  const int lane = tid & 63;
  const int cl = lane & 15;
  const int rg = lane >> 4;
  const int tile = blockIdx.x & 63;       // batch tile
  const int tg = blockIdx.x >> 6;         // time group, 4 steps each
  const int row0 = tile * 16;
  const int c0 = wid * 32;

  __shared__ __align__(16) unsigned short sT2[2][16 * 128];
  const f32x4 vzero = {0.f, 0.f, 0.f, 0.f};

  bf16x8 wp1f[2][4];
#pragma unroll
  for (int tl = 0; tl < 2; ++tl)
#pragma unroll
    for (int kt = 0; kt < 4; ++kt) wp1f[tl][kt] = load_wfrag(Wp1, 128, c0 + tl * 16, kt * 32, cl, rg);
  bf16x8 wp2f[4];
  if (wid < 2) {
#pragma unroll
    for (int kt = 0; kt < 4; ++kt) wp2f[kt] = load_wfrag(Wp2, 128, wid * 16, kt * 32, cl, rg);
  } else {
#pragma unroll
    for (int kt = 0; kt < 4; ++kt) wp2f[kt] = bf16x8{0, 0, 0, 0, 0, 0, 0, 0};
  }
  float bp1l[2] = {bp1[c0 + cl], bp1[c0 + 16 + cl]};
  const float bp2l = (wid < 2) ? bp2[wid * 16 + cl] : 0.f;

#pragma unroll 1
  for (int i = 0; i < 4; ++i) {
    const int tt = 257 + tg * 4 + i;
    const float* xb = X + (size_t)tt * (NBATCH * 128);
    bf16x8 aX[4];
#pragma unroll
    for (int kt = 0; kt < 4; ++kt) aX[kt] = load_wfrag(xb, 128, row0, kt * 32, cl, rg);
#pragma unroll
    for (int tl = 0; tl < 2; ++tl) {
      f32x4 acc = vzero;
#pragma unroll
      for (int kt = 0; kt < 4; ++kt) acc = MFMA16(aX[kt], wp1f[tl][kt], acc);
      f32x4 tv;
#pragma unroll
      for (int r = 0; r < 4; ++r) tv[r] = ftanh(acc[r] + bp1l[tl]);
      store_c_lds<256, 8>(sT2[i & 1], c0 + tl * 16, tv, cl, rg);
    }
    __syncthreads();
    if (wid < 2) {
      bf16x8 at[4];
#pragma unroll
      for (int kt = 0; kt < 4; ++kt) at[kt] = lds_afrag<256, 8>(sT2[i & 1], kt, cl, rg);
      f32x4 acc = vzero;
#pragma unroll
      for (int kt = 0; kt < 4; ++kt) acc = MFMA16(at[kt], wp2f[kt], acc);
      f32x4 y;
#pragma unroll
      for (int r = 0; r < 4; ++r) y[r] = acc[r] + bp2l;
      store_c_glb(outY + (size_t)tt * (NBATCH * 32) + (size_t)row0 * 32, 32, wid * 16, y, cl, rg);
    }
  }
}

extern "C" void kernel_launch(void* const* d_in, const int* in_sizes, int n_in,
                              void* d_out, int out_size, void* d_ws, size_t ws_size,
                              hipStream_t stream) {
  (void)in_sizes; (void)n_in; (void)out_size; (void)d_ws; (void)ws_size;
  const float* Y0   = (const float*)d_in[0];
  const float* Wq   = (const float*)d_in[1];
  const float* bq   = (const float*)d_in[2];
  const float* Wp1  = (const float*)d_in[3];
  const float* bp1  = (const float*)d_in[4];
  const float* Wp2  = (const float*)d_in[5];
  const float* bp2  = (const float*)d_in[6];
  const float* Ww   = (const float*)d_in[7];
  const float* bw   = (const float*)d_in[8];
  const float* Wih0 = (const float*)d_in[9];
  const float* Whh0 = (const float*)d_in[10];
  const float* bih0 = (const float*)d_in[11];
  const float* bhh0 = (const float*)d_in[12];
  const float* Wih1 = (const float*)d_in[13];
  const float* Whh1 = (const float*)d_in[14];
  const float* bih1 = (const float*)d_in[15];
  const float* bhh1 = (const float*)d_in[16];

  float* outX = (float*)d_out;
  float* outW = outX + XLEN;
  float* outY = outW + WLEN;

  sinkbf_kernel<<<dim3(NBATCH / 16), dim3(512), 0, stream>>>(
      Y0, Wq, bq, Wp1, bp1, Wp2, bp2, Ww, bw,
      Wih0, Whh0, bih0, bhh0, Wih1, Whh1, bih1, bhh1,
      outX, outW, outY);

  // horizon Yhat from streamed X (same stream -> ordered after main kernel)
  yhat_hrzn_kernel<<<dim3(64 * 64), dim3(256), 0, stream>>>(
      outX, Wp1, bp1, Wp2, bp2, outY);
}

// Round 8
// 1843.595 us; speedup vs baseline: 1.1966x; 1.0040x over previous
//
#include <hip/hip_runtime.h>

// Fixed problem dims: NX=128, NW=64, NY=32, NLAYER=2, NWUP=256, NBATCH=1024, NHRZN=256
#define NBATCH 1024
#define TSTEPS 512
#define NWUPC  256

// Output layout in d_out (fp32, flat, concatenated in return order):
//   X    (513,1024,128) : 67239936
//   W    (256,1024, 64) : 16777216
//   Yhat (513,1024, 32) : 16809984
#define XLEN 67239936ULL
#define WLEN 16777216ULL

typedef __attribute__((ext_vector_type(8))) short bf16x8;  // 8 bf16 in 4 VGPRs
typedef __attribute__((ext_vector_type(4))) float f32x4;   // MFMA 16x16 C/D

__device__ __forceinline__ unsigned short to_bf16u(float f) {
  union { float f; unsigned u; } v; v.f = f;
  unsigned r = (v.u + 0x7FFFu + ((v.u >> 16) & 1u)) >> 16;  // RNE (init-time paths)
  return (unsigned short)r;
}
__device__ __forceinline__ float bf16_to_f(short h) {
  union { unsigned u; float f; } v;
  v.u = ((unsigned)(unsigned short)h) << 16;
  return v.f;
}
// HW packed f32->bf16 (RNE); no builtin on gfx950 -> inline asm (T12/m240).
__device__ __forceinline__ unsigned cvt_pk_bf16(float lo, float hi) {
  unsigned r;
  asm("v_cvt_pk_bf16_f32 %0, %1, %2" : "=v"(r) : "v"(lo), "v"(hi));
  return r;
}
// clampless: |u| <~ 10 by weight scale (0.05) and bounded h; exp safe to ~88.
__device__ __forceinline__ float ftanh(float x) {
  float e = __expf(2.f * x);
  return (e - 1.f) * __builtin_amdgcn_rcpf(e + 1.f);
}

// lgkmcnt-only barrier, m201-exact pattern: volatile asm WITHOUT "memory"
// clobber (a memory clobber sets mayLoad/mayStore on the INLINEASM and
// SIInsertWaitcnts then drains vmcnt(0) before it -> every global store
// stalls the barrier; the R1-R7 mystery ~1900cy/phase). sched_barrier(0)
// on both sides pins scheduler motion of LDS ops (rule #18).
__device__ __forceinline__ void fast_barrier() {
  __builtin_amdgcn_sched_barrier(0);
  asm volatile("s_waitcnt lgkmcnt(0)");
  __builtin_amdgcn_s_barrier();
  __builtin_amdgcn_sched_barrier(0);
}

#define MFMA16(a, b, c) __builtin_amdgcn_mfma_f32_16x16x32_bf16((a), (b), (c), 0, 0, 0)

// B-fragment of W^T for out = in @ W.T, W row-major (N,K):
// lane holds W[rowbase + (lane&15)][kbase + 8*(lane>>4) + v], v=0..7
__device__ __forceinline__ bf16x8 load_wfrag(const float* __restrict__ W, int ldk,
                                             int rowbase, int kbase, int cl, int rg) {
  const float* p = W + (size_t)(rowbase + cl) * (size_t)ldk + (size_t)(kbase + rg * 8);
  float4 a = *reinterpret_cast<const float4*>(p);
  float4 b = *reinterpret_cast<const float4*>(p + 4);
  bf16x8 r;
  r[0] = (short)to_bf16u(a.x); r[1] = (short)to_bf16u(a.y);
  r[2] = (short)to_bf16u(a.z); r[3] = (short)to_bf16u(a.w);
  r[4] = (short)to_bf16u(b.x); r[5] = (short)to_bf16u(b.y);
  r[6] = (short)to_bf16u(b.z); r[7] = (short)to_bf16u(b.w);
  return r;
}

// A-fragment read from a bf16 [16][ROWB/2] LDS tile, XOR-swizzled 16B chunks.
template <int ROWB, int SLOTS>
__device__ __forceinline__ bf16x8 lds_afrag(const unsigned short* buf, int kt, int cl, int rg) {
  int chunk = (kt * 4 + rg) ^ (cl & (SLOTS - 1));
  return *reinterpret_cast<const bf16x8*>(
      reinterpret_cast<const char*>(buf) + cl * ROWB + chunk * 16);
}

// C-frag (col=lane&15, row=(lane>>4)*4+reg) -> bf16 LDS tile, matching swizzle.
template <int ROWB, int SLOTS>
__device__ __forceinline__ void store_c_lds(unsigned short* buf, int colbase, f32x4 v,
                                            int cl, int rg) {
  unsigned p01 = cvt_pk_bf16(v[0], v[1]);
  unsigned p23 = cvt_pk_bf16(v[2], v[3]);
  unsigned hh[4] = {p01, p01 >> 16, p23, p23 >> 16};
  int col = colbase + cl;
#pragma unroll
  for (int r = 0; r < 4; ++r) {
    int row = rg * 4 + r;
    int chunk = (col >> 3) ^ (row & (SLOTS - 1));
    *reinterpret_cast<unsigned short*>(
        reinterpret_cast<char*>(buf) + row * ROWB + chunk * 16 + (col & 7) * 2) =
        (unsigned short)hh[r];
  }
}

__device__ __forceinline__ void store_c_glb(float* __restrict__ base, int ld, int colbase,
                                            f32x4 v, int cl, int rg) {
#pragma unroll
  for (int r = 0; r < 4; ++r) base[(rg * 4 + r) * ld + colbase + cl] = v[r];
}

// packed-fragment LDS blocks: frag f at [f*512, +512) ushorts, lane-major (conflict-free)
__device__ __forceinline__ bf16x8 read_pfrag(const unsigned short* buf, int f, int lane) {
  return *reinterpret_cast<const bf16x8*>(buf + f * 512 + lane * 8);
}

// 8 waves/block, each owns 16 h-cols -> weight frags fit the 256-reg unified
// budget (VGPR+AGPR) at 2 waves/SIMD without spill (R4-verified).
__global__ __launch_bounds__(512, 2) void sinkbf_kernel(
    const float* __restrict__ Y0, const float* __restrict__ Wq, const float* __restrict__ bq,
    const float* __restrict__ Wp1, const float* __restrict__ bp1,
    const float* __restrict__ Wp2, const float* __restrict__ bp2,
    const float* __restrict__ Ww, const float* __restrict__ bw,
    const float* __restrict__ Wih0, const float* __restrict__ Whh0,
    const float* __restrict__ bih0, const float* __restrict__ bhh0,
    const float* __restrict__ Wih1, const float* __restrict__ Whh1,
    const float* __restrict__ bih1, const float* __restrict__ bhh1,
    float* __restrict__ outX, float* __restrict__ outW, float* __restrict__ outY) {
  const int tid = threadIdx.x;
  const int wid = tid >> 6;        // wave 0..7, owns h-cols [wid*16, wid*16+16)
  const int lane = tid & 63;
  const int cl = lane & 15;
  const int rg = lane >> 4;
  const int row0 = blockIdx.x * 16;  // batch tile
  const int c0 = wid * 16;

  __shared__ __align__(16) unsigned short sH0[2][16 * 128];
  __shared__ __align__(16) unsigned short sH1[2][16 * 128];
  __shared__ __align__(16) unsigned short sWb[16 * 64];
  __shared__ __align__(16) unsigned short sT[16 * 128];
  __shared__ __align__(16) unsigned short sYh[16 * 32];
  __shared__ __align__(16) unsigned short sWwP[20 * 512];
  __shared__ __align__(16) unsigned short sWp1P[32 * 512];
  __shared__ __align__(16) unsigned short sWp2P[8 * 512];

  const f32x4 vzero = {0.f, 0.f, 0.f, 0.f};

  // ---- persistent register-resident weight B-fragments (16 cols/wave) ----
  bf16x8 wI0[3][2];  // Wih0 (384,64)
  bf16x8 wH0[3][4];  // Whh0 (384,128)
  bf16x8 wI1[3][4];  // Wih1 (384,128)
  bf16x8 wH1[3][4];  // Whh1 (384,128)
#pragma unroll
  for (int g = 0; g < 3; ++g) {
    int rb = g * 128 + c0;
#pragma unroll
    for (int kt = 0; kt < 2; ++kt) wI0[g][kt] = load_wfrag(Wih0, 64, rb, kt * 32, cl, rg);
#pragma unroll
    for (int kt = 0; kt < 4; ++kt) wH0[g][kt] = load_wfrag(Whh0, 128, rb, kt * 32, cl, rg);
#pragma unroll
    for (int kt = 0; kt < 4; ++kt) wI1[g][kt] = load_wfrag(Wih1, 128, rb, kt * 32, cl, rg);
#pragma unroll
    for (int kt = 0; kt < 4; ++kt) wH1[g][kt] = load_wfrag(Whh1, 128, rb, kt * 32, cl, rg);
  }

  // ---- pack small weights to LDS as fragments ----
  if (wid < 4) {
#pragma unroll
    for (int kt = 0; kt < 5; ++kt) {  // Ww (64,160): waves 0-3 own w-cols [wid*16,+16)
      bf16x8 f = load_wfrag(Ww, 160, wid * 16, kt * 32, cl, rg);
      *reinterpret_cast<bf16x8*>(&sWwP[(wid * 5 + kt) * 512 + lane * 8]) = f;
    }
  }
#pragma unroll
  for (int kt = 0; kt < 4; ++kt) {  // Wp1 (128,128): each wave its 16 cols
    bf16x8 f = load_wfrag(Wp1, 128, c0, kt * 32, cl, rg);
    *reinterpret_cast<bf16x8*>(&sWp1P[(wid * 4 + kt) * 512 + lane * 8]) = f;
  }
  if (wid < 2) {
#pragma unroll
    for (int kt = 0; kt < 4; ++kt) {  // Wp2 (32,128): waves 0,1 own 16 y-cols
      bf16x8 f = load_wfrag(Wp2, 128, wid * 16, kt * 32, cl, rg);
      *reinterpret_cast<bf16x8*>(&sWp2P[(wid * 4 + kt) * 512 + lane * 8]) = f;
    }
  }

  // ---- per-lane biases (fp32) ----
  const int c = c0 + cl;
  const float b0r = bih0[c] + bhh0[c];
  const float b0z = bih0[128 + c] + bhh0[128 + c];
  const float b0in = bih0[256 + c];
  const float b0hn = bhh0[256 + c];
  const float b1r = bih1[c] + bhh1[c];
  const float b1z = bih1[128 + c] + bhh1[128 + c];
  const float b1in = bih1[256 + c];
  const float b1hn = bhh1[256 + c];
  const float bp1l = bp1[c];
  const float bwl = bw[(wid & 3) * 16 + cl];
  const float bp2l = (wid < 2) ? bp2[wid * 16 + cl] : 0.f;

  f32x4 hp0, hp1;  // fp32 master copy of this wave's own h columns

  // ---- init: x0 = tanh(Y0[0] @ Wq.T + bq) ----
  {
    bf16x8 aY = load_wfrag(Y0, 32, row0, 0, cl, rg);
    bf16x8 q0 = load_wfrag(Wq, 32, c0, 0, cl, rg);
    bf16x8 q1 = load_wfrag(Wq, 32, 128 + c0, 0, cl, rg);
    float bq0v = bq[c];
    float bq1v = bq[128 + c];
    f32x4 acc = MFMA16(aY, q0, vzero);
#pragma unroll
    for (int r = 0; r < 4; ++r) hp0[r] = ftanh(acc[r] + bq0v);
    store_c_lds<256, 8>(sH0[0], c0, hp0, cl, rg);
    acc = MFMA16(aY, q1, vzero);
#pragma unroll
    for (int r = 0; r < 4; ++r) hp1[r] = ftanh(acc[r] + bq1v);
    store_c_lds<256, 8>(sH1[0], c0, hp1, cl, rg);
    store_c_glb(outX + (size_t)row0 * 128, 128, c0, hp1, cl, rg);  // X[0]
  }
  __syncthreads();

  // ---- Y0 prefetch registers (one step ahead; waves 0-3 only) ----
  float4 yA, yB;
  if (wid < 4) {
    const float* py = Y0 + (size_t)1 * (NBATCH * 32) + (size_t)(row0 + cl) * 32 + rg * 8;
    yA = *reinterpret_cast<const float4*>(py);
    yB = *reinterpret_cast<const float4*>(py + 4);
  }

  // carried output pointers (strength-reduced addressing)
  float* pX = outX + (size_t)(NBATCH * 128) + (size_t)row0 * 128;  // X[1+t]
  float* pW = outW + (size_t)row0 * 64;                            // W[t]
  float* pY = outY + (size_t)row0 * 32;                            // Yhat[t]

  // ---- P phase: t = tanh(h1@Wp1.T+bp1); yhat = t@Wp2.T+bp2 (warmup only) ----
  auto p_phase = [&](float* yout, const unsigned short* h1buf) {
    bf16x8 a1[4];
#pragma unroll
    for (int kt = 0; kt < 4; ++kt) a1[kt] = lds_afrag<256, 8>(h1buf, kt, cl, rg);
    f32x4 acc = vzero;
#pragma unroll
    for (int kt = 0; kt < 4; ++kt)
      acc = MFMA16(a1[kt], read_pfrag(sWp1P, wid * 4 + kt, lane), acc);
    f32x4 tv;
#pragma unroll
    for (int r = 0; r < 4; ++r) tv[r] = ftanh(acc[r] + bp1l);
    store_c_lds<256, 8>(sT, c0, tv, cl, rg);
    fast_barrier();
    if (wid < 2) {
      bf16x8 at[4];
#pragma unroll
      for (int kt = 0; kt < 4; ++kt) at[kt] = lds_afrag<256, 8>(sT, kt, cl, rg);
      f32x4 acc2 = vzero;
#pragma unroll
      for (int kt = 0; kt < 4; ++kt) acc2 = MFMA16(at[kt], read_pfrag(sWp2P, wid * 4 + kt, lane), acc2);
      f32x4 y;
#pragma unroll
      for (int r = 0; r < 4; ++r) y[r] = acc2[r] + bp2l;
      store_c_glb(yout, 32, wid * 16, y, cl, rg);
      store_c_lds<64, 4>(sYh, wid * 16, y, cl, rg);
    }
    fast_barrier();
  };

  p_phase(pY, sH1[0]);  // yhat0
  pY += NBATCH * 32;

  // ======================= main scan =======================
#pragma unroll 1
  for (int t = 0; t < TSTEPS; ++t) {
    const int cur = t & 1, nxt = cur ^ 1;
    const unsigned short* h0c = sH0[cur];
    unsigned short* h0w = sH0[nxt];
    const unsigned short* h1c = sH1[cur];
    unsigned short* h1w = sH1[nxt];
    const bool warm = (t < NWUPC);

    bf16x8 aH0[4];
#pragma unroll
    for (int kt = 0; kt < 4; ++kt) aH0[kt] = lds_afrag<256, 8>(h0c, kt, cl, rg);

    // ---- W phase (warmup only; else w==0 so gi0 = bias) ----
    if (warm) {
      if (wid < 4) {
        bf16x8 ae;  // e = Y0[1+t] - yhat
        {
          int chunk = rg ^ (cl & 3);
          bf16x8 yh = *reinterpret_cast<const bf16x8*>(
              reinterpret_cast<const char*>(sYh) + cl * 64 + chunk * 16);
          union { bf16x8 v; uint4 u; } aeu;
          aeu.u.x = cvt_pk_bf16(yA.x - bf16_to_f(yh[0]), yA.y - bf16_to_f(yh[1]));
          aeu.u.y = cvt_pk_bf16(yA.z - bf16_to_f(yh[2]), yA.w - bf16_to_f(yh[3]));
          aeu.u.z = cvt_pk_bf16(yB.x - bf16_to_f(yh[4]), yB.y - bf16_to_f(yh[5]));
          aeu.u.w = cvt_pk_bf16(yB.z - bf16_to_f(yh[6]), yB.w - bf16_to_f(yh[7]));
          ae = aeu.v;
        }
        if (t + 1 < NWUPC) {  // prefetch next y — stays in flight across barriers
          const float* py = Y0 + (size_t)(2 + t) * (NBATCH * 32) + (size_t)(row0 + cl) * 32 + rg * 8;
          yA = *reinterpret_cast<const float4*>(py);
          yB = *reinterpret_cast<const float4*>(py + 4);
        }
        f32x4 acc = vzero;
#pragma unroll
        for (int kt = 0; kt < 4; ++kt)
          acc = MFMA16(aH0[kt], read_pfrag(sWwP, wid * 5 + kt, lane), acc);
        acc = MFMA16(ae, read_pfrag(sWwP, wid * 5 + 4, lane), acc);
        f32x4 wv;
#pragma unroll
        for (int r = 0; r < 4; ++r) wv[r] = ftanh(acc[r] + bwl);
        store_c_lds<128, 8>(sWb, wid * 16, wv, cl, rg);
        store_c_glb(pW, 64, wid * 16, wv, cl, rg);
      }
      fast_barrier();  // sWb visible to all waves
    }

    // ---- layer 0 ----
    f32x4 ar0i = vzero, az0i = vzero, ain0 = vzero;
    if (warm) {
      bf16x8 aw0 = lds_afrag<128, 8>(sWb, 0, cl, rg);
      bf16x8 aw1 = lds_afrag<128, 8>(sWb, 1, cl, rg);
      ar0i = MFMA16(aw0, wI0[0][0], ar0i);  ar0i = MFMA16(aw1, wI0[0][1], ar0i);
      az0i = MFMA16(aw0, wI0[1][0], az0i);  az0i = MFMA16(aw1, wI0[1][1], az0i);
      ain0 = MFMA16(aw0, wI0[2][0], ain0);  ain0 = MFMA16(aw1, wI0[2][1], ain0);
    }
    f32x4 ar0h = vzero, az0h = vzero, ahn0 = vzero;
#pragma unroll
    for (int kt = 0; kt < 4; ++kt) {
      ar0h = MFMA16(aH0[kt], wH0[0][kt], ar0h);
      az0h = MFMA16(aH0[kt], wH0[1][kt], az0h);
      ahn0 = MFMA16(aH0[kt], wH0[2][kt], ahn0);
    }
    f32x4 h0new;
#pragma unroll
    for (int r = 0; r < 4; ++r) {
      float ur = ar0i[r] + ar0h[r] + b0r;
      float uz = az0i[r] + az0h[r] + b0z;
      float rr = __builtin_amdgcn_rcpf(1.f + __expf(-ur));
      float s  = __builtin_amdgcn_rcpf(1.f + __expf(uz));   // s = 1 - z
      float ng = ftanh(ain0[r] + b0in + rr * (ahn0[r] + b0hn));
      h0new[r] = hp0[r] + s * (ng - hp0[r]);
    }
    store_c_lds<256, 8>(h0w, c0, h0new, cl, rg);
    hp0 = h0new;
    fast_barrier();  // h0_new visible

    // ---- layer 1: gi1(A=h0_new) + gh1(A=h1_prev) ----
    bf16x8 aH0n[4], aH1[4];
#pragma unroll
    for (int kt = 0; kt < 4; ++kt) aH0n[kt] = lds_afrag<256, 8>(h0w, kt, cl, rg);
#pragma unroll
    for (int kt = 0; kt < 4; ++kt) aH1[kt] = lds_afrag<256, 8>(h1c, kt, cl, rg);
    f32x4 ar1i = vzero, az1i = vzero, ain1 = vzero;
    f32x4 ar1h = vzero, az1h = vzero, ahn1 = vzero;
#pragma unroll
    for (int kt = 0; kt < 4; ++kt) {
      ar1i = MFMA16(aH0n[kt], wI1[0][kt], ar1i);
      az1i = MFMA16(aH0n[kt], wI1[1][kt], az1i);
      ain1 = MFMA16(aH0n[kt], wI1[2][kt], ain1);
      ar1h = MFMA16(aH1[kt], wH1[0][kt], ar1h);
      az1h = MFMA16(aH1[kt], wH1[1][kt], az1h);
      ahn1 = MFMA16(aH1[kt], wH1[2][kt], ahn1);
    }
    f32x4 h1new;
#pragma unroll
    for (int r = 0; r < 4; ++r) {
      float ur = ar1i[r] + ar1h[r] + b1r;
      float uz = az1i[r] + az1h[r] + b1z;
      float rr = __builtin_amdgcn_rcpf(1.f + __expf(-ur));
      float s  = __builtin_amdgcn_rcpf(1.f + __expf(uz));   // s = 1 - z
      float ng = ftanh(ain1[r] + b1in + rr * (ahn1[r] + b1hn));
      h1new[r] = hp1[r] + s * (ng - hp1[r]);
    }
    store_c_lds<256, 8>(h1w, c0, h1new, cl, rg);
    store_c_glb(pX, 128, c0, h1new, cl, rg);
    hp1 = h1new;
    fast_barrier();  // h1_new visible

    if (warm) {
      p_phase(pY, h1w);  // yhat needed only while e feeds back
    }

    pX += NBATCH * 128;
    pW += NBATCH * 64;
    pY += NBATCH * 32;
  }
}

// Horizon Yhat: Yhat[tt] = tanh(X[tt]@Wp1.T+bp1)@Wp2.T+bp2, tt in [257,512].
// Fully parallel over (tt, batch); same math/rounding as the inline P path.
__global__ __launch_bounds__(256, 1) void yhat_hrzn_kernel(
    const float* __restrict__ X, const float* __restrict__ Wp1, const float* __restrict__ bp1,
    const float* __restrict__ Wp2, const float* __restrict__ bp2, float* __restrict__ outY) {
  const int tid = threadIdx.x;
  const int wid = tid >> 6;
  const int lane = tid & 63;
  const int cl = lane & 15;
  const int rg = lane >> 4;
  const int tile = blockIdx.x & 63;       // batch tile
  const int tg = blockIdx.x >> 6;         // time group, 4 steps each
  const int row0 = tile * 16;
  const int c0 = wid * 32;

  __shared__ __align__(16) unsigned short sT2[2][16 * 128];
  const f32x4 vzero = {0.f, 0.f, 0.f, 0.f};

  bf16x8 wp1f[2][4];
#pragma unroll
  for (int tl = 0; tl < 2; ++tl)
#pragma unroll
    for (int kt = 0; kt < 4; ++kt) wp1f[tl][kt] = load_wfrag(Wp1, 128, c0 + tl * 16, kt * 32, cl, rg);
  bf16x8 wp2f[4];
  if (wid < 2) {
#pragma unroll
    for (int kt = 0; kt < 4; ++kt) wp2f[kt] = load_wfrag(Wp2, 128, wid * 16, kt * 32, cl, rg);
  } else {
#pragma unroll
    for (int kt = 0; kt < 4; ++kt) wp2f[kt] = bf16x8{0, 0, 0, 0, 0, 0, 0, 0};
  }
  float bp1l[2] = {bp1[c0 + cl], bp1[c0 + 16 + cl]};
  const float bp2l = (wid < 2) ? bp2[wid * 16 + cl] : 0.f;

#pragma unroll 1
  for (int i = 0; i < 4; ++i) {
    const int tt = 257 + tg * 4 + i;
    const float* xb = X + (size_t)tt * (NBATCH * 128);
    bf16x8 aX[4];
#pragma unroll
    for (int kt = 0; kt < 4; ++kt) aX[kt] = load_wfrag(xb, 128, row0, kt * 32, cl, rg);
#pragma unroll
    for (int tl = 0; tl < 2; ++tl) {
      f32x4 acc = vzero;
#pragma unroll
      for (int kt = 0; kt < 4; ++kt) acc = MFMA16(aX[kt], wp1f[tl][kt], acc);
      f32x4 tv;
#pragma unroll
      for (int r = 0; r < 4; ++r) tv[r] = ftanh(acc[r] + bp1l[tl]);
      store_c_lds<256, 8>(sT2[i & 1], c0 + tl * 16, tv, cl, rg);
    }
    __syncthreads();
    if (wid < 2) {
      bf16x8 at[4];
#pragma unroll
      for (int kt = 0; kt < 4; ++kt) at[kt] = lds_afrag<256, 8>(sT2[i & 1], kt, cl, rg);
      f32x4 acc = vzero;
#pragma unroll
      for (int kt = 0; kt < 4; ++kt) acc = MFMA16(at[kt], wp2f[kt], acc);
      f32x4 y;
#pragma unroll
      for (int r = 0; r < 4; ++r) y[r] = acc[r] + bp2l;
      store_c_glb(outY + (size_t)tt * (NBATCH * 32) + (size_t)row0 * 32, 32, wid * 16, y, cl, rg);
    }
  }
}

extern "C" void kernel_launch(void* const* d_in, const int* in_sizes, int n_in,
                              void* d_out, int out_size, void* d_ws, size_t ws_size,
                              hipStream_t stream) {
  (void)in_sizes; (void)n_in; (void)out_size; (void)d_ws; (void)ws_size;
  const float* Y0   = (const float*)d_in[0];
  const float* Wq   = (const float*)d_in[1];
  const float* bq   = (const float*)d_in[2];
  const float* Wp1  = (const float*)d_in[3];
  const float* bp1  = (const float*)d_in[4];
  const float* Wp2  = (const float*)d_in[5];
  const float* bp2  = (const float*)d_in[6];
  const float* Ww   = (const float*)d_in[7];
  const float* bw   = (const float*)d_in[8];
  const float* Wih0 = (const float*)d_in[9];
  const float* Whh0 = (const float*)d_in[10];
  const float* bih0 = (const float*)d_in[11];
  const float* bhh0 = (const float*)d_in[12];
  const float* Wih1 = (const float*)d_in[13];
  const float* Whh1 = (const float*)d_in[14];
  const float* bih1 = (const float*)d_in[15];
  const float* bhh1 = (const float*)d_in[16];

  float* outX = (float*)d_out;
  float* outW = outX + XLEN;
  float* outY = outW + WLEN;

  sinkbf_kernel<<<dim3(NBATCH / 16), dim3(512), 0, stream>>>(
      Y0, Wq, bq, Wp1, bp1, Wp2, bp2, Ww, bw,
      Wih0, Whh0, bih0, bhh0, Wih1, Whh1, bih1, bhh1,
      outX, outW, outY);

  // horizon Yhat from streamed X (same stream -> ordered after main kernel)
  yhat_hrzn_kernel<<<dim3(64 * 64), dim3(256), 0, stream>>>(
      outX, Wp1, bp1, Wp2, bp2, outY);
}